// Round 4
// baseline (42.465 us; speedup 1.0000x reference)
//
#include <hip/hip_runtime.h>
#include <hip/hip_bf16.h>

// Problem: B=8192, A=128, F=16, S=8
// x[b,a,:] = c[b,a,:] - q[b,a,:] * lam[b, seg[b,a]]
// lam[b,s] = (sum_{a: seg=s} c.q - charges[b,s]) / (sum_{a: seg=s} q.q)
//
// R4: wave-per-batch, no LDS/barriers/atomics (as R3), plus:
//  - fold-by-2 butterfly: 34 shfl instead of 96 (values halve as lanes halve)
//  - non-temporal stores: keep the 64MB write stream from evicting the
//    L3-resident c/q read set between replays

#define B_ 8192
#define A_ 128
#define F_ 16
#define S_ 8

#define WPB 4                       // waves (=batches) per block
#define VPB (A_ * F_ / 4)           // 512 float4 per batch
#define VPL (VPB / 64)              // 8 float4 per lane

typedef float f4 __attribute__((ext_vector_type(4)));

__global__ __launch_bounds__(64 * WPB) void qp_seg_norm_kernel(
    const float* __restrict__ c_iso,
    const float* __restrict__ int_iso,
    const int*   __restrict__ segment,
    const float* __restrict__ charges,
    float*       __restrict__ out)
{
    const int w    = threadIdx.x >> 6;
    const int lane = threadIdx.x & 63;
    const int b    = blockIdx.x * WPB + w;

    // Segment this lane will own after the fold-reduction (bit-reversed map):
    // final array index a = bit0*8 + bit1*4 + bit2*2 + bit3; even-bit0 lanes
    // own qc[s], s = bit1*4 + bit2*2 + bit3.
    const int sl = ((lane >> 1) & 1) * 4 + ((lane >> 2) & 1) * 2 + ((lane >> 3) & 1);
    const float charge = charges[(size_t)b * S_ + sl];   // hoisted, 32B/b, L1

    const f4* cp = reinterpret_cast<const f4*>(c_iso)   + (size_t)b * VPB;
    const f4* qp = reinterpret_cast<const f4*>(int_iso) + (size_t)b * VPB;
    const int* sp = segment + (size_t)b * A_;

    f4 cv[VPL], qv[VPL];
    unsigned sgp = 0;                // 8 segment ids packed 4 bits each

#pragma unroll
    for (int j = 0; j < VPL; ++j) {
        const int v = j * 64 + lane;           // coalesced float4 groups
        cv[j] = cp[v];
        qv[j] = qp[v];
        sgp |= ((unsigned)sp[v >> 2]) << (4 * j);
    }

    // Branchless per-segment accumulate: val[s]=qc sums, val[8+s]=qq sums.
    float val[16];
#pragma unroll
    for (int k = 0; k < 16; ++k) val[k] = 0.0f;

#pragma unroll
    for (int j = 0; j < VPL; ++j) {
        const float cq = cv[j].x * qv[j].x + cv[j].y * qv[j].y
                       + cv[j].z * qv[j].z + cv[j].w * qv[j].w;
        const float qq = qv[j].x * qv[j].x + qv[j].y * qv[j].y
                       + qv[j].z * qv[j].z + qv[j].w * qv[j].w;
        const int sj = (int)((sgp >> (4 * j)) & 7u);
#pragma unroll
        for (int s = 0; s < S_; ++s) {
            const bool m = (sj == s);
            val[s]      += m ? cq : 0.0f;
            val[8 + s]  += m ? qq : 0.0f;
        }
    }

    // Fold-by-2 butterfly: 16+8+4+2+1+1 = 32 shfl (+2 epilogue).
#pragma unroll
    for (int k = 0; k < 16; ++k) val[k] += __shfl_xor(val[k], 1, 64);
    float v8[8];
#pragma unroll
    for (int k = 0; k < 8; ++k) v8[k] = (lane & 1) ? val[8 + k] : val[k];
#pragma unroll
    for (int k = 0; k < 8; ++k) v8[k] += __shfl_xor(v8[k], 2, 64);
    float v4a[4];
#pragma unroll
    for (int k = 0; k < 4; ++k) v4a[k] = (lane & 2) ? v8[4 + k] : v8[k];
#pragma unroll
    for (int k = 0; k < 4; ++k) v4a[k] += __shfl_xor(v4a[k], 4, 64);
    float v2a[2];
#pragma unroll
    for (int k = 0; k < 2; ++k) v2a[k] = (lane & 4) ? v4a[2 + k] : v4a[k];
#pragma unroll
    for (int k = 0; k < 2; ++k) v2a[k] += __shfl_xor(v2a[k], 8, 64);
    float v1 = (lane & 8) ? v2a[1] : v2a[0];
    v1 += __shfl_xor(v1, 16, 64);
    v1 += __shfl_xor(v1, 32, 64);

    // Even-bit0 lanes hold qc[sl]; partner (lane^1) holds qq[sl].
    const float prt = __shfl_xor(v1, 1, 64);
    const float lamv = (v1 - charge) / prt;   // valid where (lane&1)==0

    // lane owning lam for segment s: L(s) = bitrev placement, packed nibbles
    // s=0..7 -> 0,8,4,12,2,10,6,14
    const unsigned Ltab = 0xE6A2C480u;

    f4* op = reinterpret_cast<f4*>(out) + (size_t)b * VPB;
#pragma unroll
    for (int j = 0; j < VPL; ++j) {
        const int sj = (int)((sgp >> (4 * j)) & 7u);
        const int src = (int)((Ltab >> (4 * sj)) & 15u);
        const float lam = __shfl(lamv, src, 64);
        const int v = j * 64 + lane;
        f4 r;
        r.x = cv[j].x - qv[j].x * lam;
        r.y = cv[j].y - qv[j].y * lam;
        r.z = cv[j].z - qv[j].z * lam;
        r.w = cv[j].w - qv[j].w * lam;
        __builtin_nontemporal_store(r, op + v);
    }
}

extern "C" void kernel_launch(void* const* d_in, const int* in_sizes, int n_in,
                              void* d_out, int out_size, void* d_ws, size_t ws_size,
                              hipStream_t stream) {
    const float* c_iso   = (const float*)d_in[0];
    const float* int_iso = (const float*)d_in[1];
    const int*   segment = (const int*)d_in[2];
    const float* charges = (const float*)d_in[3];
    float* out = (float*)d_out;

    qp_seg_norm_kernel<<<B_ / WPB, 64 * WPB, 0, stream>>>(
        c_iso, int_iso, segment, charges, out);
}

// Round 5
// 36.075 us; speedup vs baseline: 1.1771x; 1.1771x over previous
//
#include <hip/hip_runtime.h>
#include <hip/hip_bf16.h>

// Problem: B=8192, A=128, F=16, S=8
// x[b,a,:] = c[b,a,:] - q[b,a,:] * lam[b, seg[b,a]]
// lam[b,s] = (sum_{a: seg=s} c.q - charges[b,s]) / (sum_{a: seg=s} q.q)
//
// R5: R3 structure (wave-per-batch, no LDS/barrier/atomic, full butterfly,
// shfl-broadcast epilogue, NORMAL stores) with pair-atom lane mapping:
// lane l owns float4 pairs {2l+128t, 2l+1+128t}, t=0..3 -> one half-atom per
// pair -> only 4 (cq,qq,seg) triples per lane -> masked accumulate halved.

#define B_ 8192
#define A_ 128
#define F_ 16
#define S_ 8

#define WPB 4                       // waves (=batches) per block
#define VPB (A_ * F_ / 4)           // 512 float4 per batch

typedef float f4 __attribute__((ext_vector_type(4)));

__device__ __forceinline__ float dot4(const f4 a, const f4 b) {
    return a.x * b.x + a.y * b.y + a.z * b.z + a.w * b.w;
}

__global__ __launch_bounds__(64 * WPB) void qp_seg_norm_kernel(
    const float* __restrict__ c_iso,
    const float* __restrict__ int_iso,
    const int*   __restrict__ segment,
    const float* __restrict__ charges,
    float*       __restrict__ out)
{
    const int w    = threadIdx.x >> 6;
    const int lane = threadIdx.x & 63;
    const int b    = blockIdx.x * WPB + w;

    float charge = 0.0f;
    if (lane < S_) charge = charges[(size_t)b * S_ + lane];

    const f4* cp = reinterpret_cast<const f4*>(c_iso)   + (size_t)b * VPB;
    const f4* qp = reinterpret_cast<const f4*>(int_iso) + (size_t)b * VPB;
    const int* sp = segment + (size_t)b * A_;

    f4 cv[8], qv[8];
    int sg[4];

#pragma unroll
    for (int t = 0; t < 4; ++t) {
        const int v0 = 2 * lane + 128 * t;     // float4 idx (pair v0, v0+1)
        cv[2 * t]     = cp[v0];
        cv[2 * t + 1] = cp[v0 + 1];
        qv[2 * t]     = qp[v0];
        qv[2 * t + 1] = qp[v0 + 1];
        sg[t] = sp[(lane >> 1) + 32 * t];      // atom = v0>>2
    }

    // Branchless per-segment accumulate: val[s]=qc, val[8+s]=qq. 4 triples.
    float val[16];
#pragma unroll
    for (int k = 0; k < 16; ++k) val[k] = 0.0f;

#pragma unroll
    for (int t = 0; t < 4; ++t) {
        const float cq = dot4(cv[2 * t], qv[2 * t]) + dot4(cv[2 * t + 1], qv[2 * t + 1]);
        const float qq = dot4(qv[2 * t], qv[2 * t]) + dot4(qv[2 * t + 1], qv[2 * t + 1]);
        const int sj = sg[t];
#pragma unroll
        for (int s = 0; s < S_; ++s) {
            const bool m = (sj == s);
            val[s]     += m ? cq : 0.0f;
            val[8 + s] += m ? qq : 0.0f;
        }
    }

    // Full butterfly all-reduce (16 values x 6 steps) -> all lanes have sums.
#pragma unroll
    for (int m = 1; m < 64; m <<= 1) {
#pragma unroll
        for (int k = 0; k < 16; ++k) val[k] += __shfl_xor(val[k], m, 64);
    }

    // lane s (s<8) computes lam[s].
    float qcsel = val[0], qqsel = val[8];
#pragma unroll
    for (int s = 1; s < S_; ++s) {
        const bool m = (lane == s);
        qcsel = m ? val[s]     : qcsel;
        qqsel = m ? val[8 + s] : qqsel;
    }
    const float lamv = (qcsel - charge) / qqsel;   // valid in lanes 0..7

    f4* op = reinterpret_cast<f4*>(out) + (size_t)b * VPB;
#pragma unroll
    for (int t = 0; t < 4; ++t) {
        const float lam = __shfl(lamv, sg[t], 64);
        const int v0 = 2 * lane + 128 * t;
        f4 r0, r1;
        r0.x = cv[2 * t].x     - qv[2 * t].x     * lam;
        r0.y = cv[2 * t].y     - qv[2 * t].y     * lam;
        r0.z = cv[2 * t].z     - qv[2 * t].z     * lam;
        r0.w = cv[2 * t].w     - qv[2 * t].w     * lam;
        r1.x = cv[2 * t + 1].x - qv[2 * t + 1].x * lam;
        r1.y = cv[2 * t + 1].y - qv[2 * t + 1].y * lam;
        r1.z = cv[2 * t + 1].z - qv[2 * t + 1].z * lam;
        r1.w = cv[2 * t + 1].w - qv[2 * t + 1].w * lam;
        op[v0]     = r0;
        op[v0 + 1] = r1;
    }
}

extern "C" void kernel_launch(void* const* d_in, const int* in_sizes, int n_in,
                              void* d_out, int out_size, void* d_ws, size_t ws_size,
                              hipStream_t stream) {
    const float* c_iso   = (const float*)d_in[0];
    const float* int_iso = (const float*)d_in[1];
    const int*   segment = (const int*)d_in[2];
    const float* charges = (const float*)d_in[3];
    float* out = (float*)d_out;

    qp_seg_norm_kernel<<<B_ / WPB, 64 * WPB, 0, stream>>>(
        c_iso, int_iso, segment, charges, out);
}